// Round 1
// baseline (76851.129 us; speedup 1.0000x reference)
//
#include <hip/hip_runtime.h>
#include <hip/hip_bf16.h>

#define N        2048
#define T_STEPS  8192
#define DIN      64
#define KW       128     // workgroups (1 per CU due to LDS)
#define ROWS     16      // N / KW rows per WG
#define NTHR     256
#define SCOPE_AG __HIP_MEMORY_SCOPE_AGENT

// ---------------------------------------------------------------------------
// init: zero the s0 buffer and the barrier counter (d_ws is poisoned 0xAA
// before every timed launch, so this must run every call).
// ---------------------------------------------------------------------------
__global__ void init_kernel(float* sbuf, unsigned* counter) {
    int i = threadIdx.x + blockIdx.x * blockDim.x;
    if (i < N) sbuf[i] = 0.0f;          // s0 = 0 lives in sbuf[0][*]
    if (i == 0) *counter = 0u;
}

// ---------------------------------------------------------------------------
// persistent reservoir scan. One WG owns ROWS rows of W (staged once in LDS).
// Per step: coherent-load full s (8 KiB) -> LDS, 4 rows/wave matvec with
// conflict-free ds_read_b128, fused W_in·u[t] into the same wave butterfly,
// tanh+leak on 4 lanes, coherent store of the 16 new state elems, then a
// grid barrier (release add + relaxed spin + one acquire).
// ---------------------------------------------------------------------------
extern "C" __global__ void __launch_bounds__(NTHR, 1)
reservoir_scan(const float* __restrict__ W,
               const float* __restrict__ W_in,
               const float* __restrict__ u,
               const float* __restrict__ noise,
               float* __restrict__ sbuf,          // [2][N] fp32, LLC-resident
               unsigned* __restrict__ counter,
               __hip_bfloat16* __restrict__ states) // [T][N]
{
    __shared__ float Ws[ROWS][N];   // 128 KiB — W slice, staged once
    __shared__ float s_s[N];        // 8 KiB   — broadcast state
    __shared__ int   s_timeout;

    const int tid = threadIdx.x;
    const int wg  = blockIdx.x;
    const int wv  = tid >> 6;       // wave 0..3
    const int ln  = tid & 63;       // lane 0..63
    const int r0  = wg * ROWS;      // first global row of this WG
    const int rb  = wv * 4;         // first local row of this wave

    // --- stage W rows (coalesced, once) ---
    for (int idx = tid; idx < ROWS * N; idx += NTHR) {
        int r = idx >> 11, c = idx & (N - 1);
        Ws[r][c] = W[(size_t)(r0 + r) * N + c];
    }
    // --- W_in columns in registers: lane ln holds W_in[row][ln] (DIN==64) ---
    float wr0 = W_in[(size_t)(r0 + rb + 0) * DIN + ln];
    float wr1 = W_in[(size_t)(r0 + rb + 1) * DIN + ln];
    float wr2 = W_in[(size_t)(r0 + rb + 2) * DIN + ln];
    float wr3 = W_in[(size_t)(r0 + rb + 3) * DIN + ln];
    if (tid == 0) s_timeout = 0;
    __syncthreads();

    const float4* Ws4 = (const float4*)&Ws[0][0];
    const float4* s4  = (const float4*)s_s;

    for (int t = 0; t < T_STEPS; ++t) {
        const int p  = t & 1;
        const int np = p ^ 1;

        // issue independent loads early (overlap with s broadcast)
        float ul = u[t * DIN + ln];                       // u[t][lane]
        float nz = 0.0f;
        if (ln < 4) nz = noise[(size_t)t * N + r0 + rb + ln];

        // broadcast state: agent-coherent loads from LLC -> LDS
        for (int i = tid; i < N; i += NTHR)
            s_s[i] = __hip_atomic_load(&sbuf[p * N + i], __ATOMIC_RELAXED, SCOPE_AG);
        __syncthreads();

        // matvec: wave wv -> rows rb..rb+3; lane covers cols {4c + 256j}
        float a0 = wr0 * ul;   // fold input drive into the same reduction
        float a1 = wr1 * ul;
        float a2 = wr2 * ul;
        float a3 = wr3 * ul;
        #pragma unroll
        for (int j = 0; j < 8; ++j) {
            const int ci = ln + 64 * j;
            float4 sv = s4[ci];
            float4 w0 = Ws4[(rb + 0) * (N / 4) + ci];
            float4 w1 = Ws4[(rb + 1) * (N / 4) + ci];
            float4 w2 = Ws4[(rb + 2) * (N / 4) + ci];
            float4 w3 = Ws4[(rb + 3) * (N / 4) + ci];
            a0 += w0.x * sv.x + w0.y * sv.y + w0.z * sv.z + w0.w * sv.w;
            a1 += w1.x * sv.x + w1.y * sv.y + w1.z * sv.z + w1.w * sv.w;
            a2 += w2.x * sv.x + w2.y * sv.y + w2.z * sv.z + w2.w * sv.w;
            a3 += w3.x * sv.x + w3.y * sv.y + w3.z * sv.z + w3.w * sv.w;
        }
        #pragma unroll
        for (int off = 1; off < 64; off <<= 1) {
            a0 += __shfl_xor(a0, off, 64);
            a1 += __shfl_xor(a1, off, 64);
            a2 += __shfl_xor(a2, off, 64);
            a3 += __shfl_xor(a3, off, 64);
        }

        if (ln < 4) {
            const int gr  = r0 + rb + ln;                 // global row
            float acc  = (ln == 0) ? a0 : (ln == 1) ? a1 : (ln == 2) ? a2 : a3;
            float pre  = acc + 0.01f * nz;                // W@s + W_in@u + noise
            float sold = s_s[gr];
            float snew = 0.7f * sold + 0.3f * tanhf(pre);
            __hip_atomic_store(&sbuf[np * N + gr], snew, __ATOMIC_RELAXED, SCOPE_AG);
            states[(size_t)t * N + gr] = __float2bfloat16(snew);
        }

        // --- grid barrier (monotonic counter, one per step) ---
        __syncthreads();   // all waves' coherent stores drained (vmcnt)
        if (tid == 0) {
            __hip_atomic_fetch_add(counter, 1u, __ATOMIC_RELEASE, SCOPE_AG);
            const unsigned target = (unsigned)(t + 1) * KW;
            unsigned v; int guard = 0;
            for (;;) {
                v = __hip_atomic_load(counter, __ATOMIC_RELAXED, SCOPE_AG);
                if (v >= target) break;
                if (++guard > 100000) { s_timeout = 1; break; }  // ~60 ms max
                __builtin_amdgcn_s_sleep(2);
            }
            (void)__hip_atomic_load(counter, __ATOMIC_ACQUIRE, SCOPE_AG);
        }
        __syncthreads();
        if (s_timeout) return;   // uniform per WG; avoids an eternal hang
    }
}

// ---------------------------------------------------------------------------
// readout: out[t][d] = states[t] . w_out[d] + b_out[d].  One wave per t,
// lane covers cols {4c+256j}: coalesced 1 KiB global segments of w_out,
// conflict-free b128 LDS reads of s, full-wave butterfly per output.
// ---------------------------------------------------------------------------
__global__ void __launch_bounds__(256)
out_gemm(const __hip_bfloat16* __restrict__ states,
         const float* __restrict__ w_out,
         const float* __restrict__ b_out,
         float* __restrict__ out)
{
    __shared__ float s_lds[4][N];   // 32 KiB
    const int tid = threadIdx.x;
    const int wv  = tid >> 6, ln = tid & 63;
    const int t0  = blockIdx.x * 4;

    for (int idx = tid; idx < 4 * N; idx += 256) {
        int tt = idx >> 11, kk = idx & (N - 1);
        s_lds[tt][kk] = __bfloat162float(states[(size_t)(t0 + tt) * N + kk]);
    }
    __syncthreads();

    const int t = t0 + wv;
    const float4* s4 = (const float4*)&s_lds[wv][0];
    for (int d = 0; d < 64; ++d) {
        const float4* w4 = (const float4*)(w_out + (size_t)d * N);
        float a = 0.0f;
        #pragma unroll
        for (int j = 0; j < 8; ++j) {
            const int ci = ln + 64 * j;
            float4 wv4 = w4[ci];
            float4 sv  = s4[ci];
            a += wv4.x * sv.x + wv4.y * sv.y + wv4.z * sv.z + wv4.w * sv.w;
        }
        #pragma unroll
        for (int off = 1; off < 64; off <<= 1) a += __shfl_xor(a, off, 64);
        if (ln == 0) out[t * 64 + d] = a + b_out[d];
    }
}

// ---------------------------------------------------------------------------
extern "C" void kernel_launch(void* const* d_in, const int* in_sizes, int n_in,
                              void* d_out, int out_size, void* d_ws, size_t ws_size,
                              hipStream_t stream)
{
    const float* u     = (const float*)d_in[0];   // (T, DIN)
    const float* noise = (const float*)d_in[1];   // (T, N)
    const float* W_in  = (const float*)d_in[2];   // (N, DIN)
    const float* W     = (const float*)d_in[3];   // (N, N)
    const float* w_out = (const float*)d_in[4];   // (64, N)
    const float* b_out = (const float*)d_in[5];   // (64,)
    float* out = (float*)d_out;

    // workspace layout: [0,4): counter | [256, 256+16K): sbuf[2][N] fp32
    //                   [32768, 32768+32M): states bf16 (T x N)
    unsigned* counter      = (unsigned*)d_ws;
    float* sbuf            = (float*)((char*)d_ws + 256);
    __hip_bfloat16* states = (__hip_bfloat16*)((char*)d_ws + 32768);

    hipLaunchKernelGGL(init_kernel, dim3((N + 255) / 256), dim3(256), 0, stream,
                       sbuf, counter);

    void* args[] = { (void*)&W, (void*)&W_in, (void*)&u, (void*)&noise,
                     (void*)&sbuf, (void*)&counter, (void*)&states };
    hipLaunchCooperativeKernel((const void*)reservoir_scan,
                               dim3(KW), dim3(NTHR), args, 0, stream);

    hipLaunchKernelGGL(out_gemm, dim3(T_STEPS / 4), dim3(256), 0, stream,
                       states, w_out, b_out, out);
}

// Round 2
// 26391.089 us; speedup vs baseline: 2.9120x; 2.9120x over previous
//
#include <hip/hip_runtime.h>
#include <hip/hip_bf16.h>

#define N        2048
#define T_STEPS  8192
#define DIN      64
#define KW       128     // workgroups, 1 per CU
#define ROWS     16      // N / KW rows per WG
#define NTHR     256
#define SCOPE_AG __HIP_MEMORY_SCOPE_AGENT

typedef unsigned long long u64;

// ---------------------------------------------------------------------------
// Exchange buffer protocol (replaces the grid barrier):
//   ex[b][i], b = t&1, holds state s_t[i] as (fp32_bits << 32) | t.
//   Producers: one relaxed agent-scope 64-bit atomic store (value+tag atom).
//   Consumers: spin relaxed 64-bit loads until tag == t.
//   Depth-2 is sufficient: a WG can only write s_{t+2} after reading all of
//   s_{t+1}, which requires every WG to have produced s_{t+1}, which requires
//   they read all of s_t — so no slot is overwritten while still needed.
// ---------------------------------------------------------------------------

__global__ void init_kernel(u64* ex0) {
    int i = threadIdx.x + blockIdx.x * blockDim.x;
    if (i < N) ex0[i] = 0ull;   // s_0 = 0.0f, tag 0. ex[1] keeps poison tags
                                // (0xAAAAAAAA never matches any t in [0,8192]).
}

// ---------------------------------------------------------------------------
// persistent reservoir scan. W slice lives in REGISTERS (4 rows x 8 float4 =
// 128 VGPRs/thread); LDS only stages the 8 KiB broadcast state. Per step:
// spin-gather s_t (8 u64 slots/thread), matvec + fused W_in·u[t] in one
// 64-lane butterfly, tanh+leak, one tagged store per produced element.
// ---------------------------------------------------------------------------
extern "C" __global__ void __launch_bounds__(NTHR, 1)
reservoir_scan(const float* __restrict__ W,
               const float* __restrict__ W_in,
               const float* __restrict__ u,
               const float* __restrict__ noise,
               u64* __restrict__ ex,                 // [2][N] value+tag atoms
               __hip_bfloat16* __restrict__ states)  // [T][N]
{
    __shared__ float s_s[N];     // 8 KiB broadcast state
    __shared__ int   s_timeout;

    const int tid = threadIdx.x;
    const int wg  = blockIdx.x;
    const int wv  = tid >> 6;        // wave 0..3
    const int ln  = tid & 63;        // lane 0..63
    const int r0  = wg * ROWS;       // first global row of this WG
    const int rb  = wv * 4;          // first local row of this wave

    // --- W slice into registers: wr[r][j] = W[r0+rb+r][4*(ln+64j) .. +3] ---
    float4 wr[4][8];
    const float4* W4 = (const float4*)W;
    #pragma unroll
    for (int r = 0; r < 4; ++r)
        #pragma unroll
        for (int j = 0; j < 8; ++j)
            wr[r][j] = W4[(size_t)(r0 + rb + r) * (N / 4) + ln + 64 * j];

    // --- W_in columns: lane ln holds W_in[row][ln] (DIN == 64) ---
    float wi0 = W_in[(size_t)(r0 + rb + 0) * DIN + ln];
    float wi1 = W_in[(size_t)(r0 + rb + 1) * DIN + ln];
    float wi2 = W_in[(size_t)(r0 + rb + 2) * DIN + ln];
    float wi3 = W_in[(size_t)(r0 + rb + 3) * DIN + ln];
    if (tid == 0) s_timeout = 0;
    __syncthreads();

    const float4* s4   = (const float4*)s_s;
    const int     base = tid * 8;    // this thread's 8 exchange slots

    for (int t = 0; t < T_STEPS; ++t) {
        // independent loads issued early — overlap with the spin-gather
        float ul = u[t * DIN + ln];
        float nz = 0.0f;
        if (ln < 4) nz = noise[(size_t)t * N + r0 + rb + ln];

        // --- spin-gather s_t from ex[t&1] (8 pipelined u64 loads / pass) ---
        u64* exb = ex + (size_t)(t & 1) * N;
        unsigned pend = 0xFFu;
        int guard = 0;
        while (pend) {
            #pragma unroll
            for (int i = 0; i < 8; ++i) {
                if (pend & (1u << i)) {
                    u64 v = __hip_atomic_load(&exb[base + i], __ATOMIC_RELAXED, SCOPE_AG);
                    if ((unsigned)v == (unsigned)t) {
                        s_s[base + i] = __uint_as_float((unsigned)(v >> 32));
                        pend &= ~(1u << i);
                    }
                }
            }
            if (++guard > (1 << 17)) { s_timeout = 1; break; }  // safety valve
        }
        __syncthreads();
        if (s_timeout) return;   // uniform abort instead of an eternal hang

        // --- matvec: wave wv -> rows rb..rb+3; lane covers cols {4(ln+64j)} ---
        float a0 = wi0 * ul;     // input drive folded into the same reduction
        float a1 = wi1 * ul;
        float a2 = wi2 * ul;
        float a3 = wi3 * ul;
        #pragma unroll
        for (int j = 0; j < 8; ++j) {
            float4 sv = s4[ln + 64 * j];
            a0 += wr[0][j].x * sv.x + wr[0][j].y * sv.y + wr[0][j].z * sv.z + wr[0][j].w * sv.w;
            a1 += wr[1][j].x * sv.x + wr[1][j].y * sv.y + wr[1][j].z * sv.z + wr[1][j].w * sv.w;
            a2 += wr[2][j].x * sv.x + wr[2][j].y * sv.y + wr[2][j].z * sv.z + wr[2][j].w * sv.w;
            a3 += wr[3][j].x * sv.x + wr[3][j].y * sv.y + wr[3][j].z * sv.z + wr[3][j].w * sv.w;
        }
        #pragma unroll
        for (int off = 1; off < 64; off <<= 1) {
            a0 += __shfl_xor(a0, off, 64);
            a1 += __shfl_xor(a1, off, 64);
            a2 += __shfl_xor(a2, off, 64);
            a3 += __shfl_xor(a3, off, 64);
        }

        if (ln < 4) {
            const int gr = r0 + rb + ln;
            float acc  = (ln == 0) ? a0 : (ln == 1) ? a1 : (ln == 2) ? a2 : a3;
            float pre  = acc + 0.01f * nz;
            float snew = 0.7f * s_s[gr] + 0.3f * tanhf(pre);
            u64 pk = ((u64)__float_as_uint(snew) << 32) | (unsigned)(t + 1);
            __hip_atomic_store(&ex[(size_t)((t + 1) & 1) * N + gr], pk,
                               __ATOMIC_RELAXED, SCOPE_AG);
            states[(size_t)t * N + gr] = __float2bfloat16(snew);
        }

        __syncthreads();   // protect s_s before next step's gather overwrites
    }
}

// ---------------------------------------------------------------------------
// readout: out[t][d] = states[t] . w_out[d] + b_out[d].  One wave per t,
// lane covers cols {4c+256j}: coalesced global reads of w_out, conflict-free
// b128 LDS reads of s, full-wave butterfly per output.
// ---------------------------------------------------------------------------
__global__ void __launch_bounds__(256)
out_gemm(const __hip_bfloat16* __restrict__ states,
         const float* __restrict__ w_out,
         const float* __restrict__ b_out,
         float* __restrict__ out)
{
    __shared__ float s_lds[4][N];   // 32 KiB
    const int tid = threadIdx.x;
    const int wv  = tid >> 6, ln = tid & 63;
    const int t0  = blockIdx.x * 4;

    for (int idx = tid; idx < 4 * N; idx += 256) {
        int tt = idx >> 11, kk = idx & (N - 1);
        s_lds[tt][kk] = __bfloat162float(states[(size_t)(t0 + tt) * N + kk]);
    }
    __syncthreads();

    const int t = t0 + wv;
    const float4* s4 = (const float4*)&s_lds[wv][0];
    for (int d = 0; d < 64; ++d) {
        const float4* w4 = (const float4*)(w_out + (size_t)d * N);
        float a = 0.0f;
        #pragma unroll
        for (int j = 0; j < 8; ++j) {
            const int ci = ln + 64 * j;
            float4 wv4 = w4[ci];
            float4 sv  = s4[ci];
            a += wv4.x * sv.x + wv4.y * sv.y + wv4.z * sv.z + wv4.w * sv.w;
        }
        #pragma unroll
        for (int off = 1; off < 64; off <<= 1) a += __shfl_xor(a, off, 64);
        if (ln == 0) out[t * 64 + d] = a + b_out[d];
    }
}

// ---------------------------------------------------------------------------
extern "C" void kernel_launch(void* const* d_in, const int* in_sizes, int n_in,
                              void* d_out, int out_size, void* d_ws, size_t ws_size,
                              hipStream_t stream)
{
    const float* u     = (const float*)d_in[0];   // (T, DIN)
    const float* noise = (const float*)d_in[1];   // (T, N)
    const float* W_in  = (const float*)d_in[2];   // (N, DIN)
    const float* W     = (const float*)d_in[3];   // (N, N)
    const float* w_out = (const float*)d_in[4];   // (64, N)
    const float* b_out = (const float*)d_in[5];   // (64,)
    float* out = (float*)d_out;

    // workspace layout: [0, 32K): ex[2][N] u64 | [64K, 64K+32M): states bf16
    u64* ex                = (u64*)d_ws;
    __hip_bfloat16* states = (__hip_bfloat16*)((char*)d_ws + 65536);

    hipLaunchKernelGGL(init_kernel, dim3((N + 255) / 256), dim3(256), 0, stream,
                       ex);

    void* args[] = { (void*)&W, (void*)&W_in, (void*)&u, (void*)&noise,
                     (void*)&ex, (void*)&states };
    hipLaunchCooperativeKernel((const void*)reservoir_scan,
                               dim3(KW), dim3(NTHR), args, 0, stream);

    hipLaunchKernelGGL(out_gemm, dim3(T_STEPS / 4), dim3(256), 0, stream,
                       states, w_out, b_out, out);
}

// Round 3
// 15472.939 us; speedup vs baseline: 4.9668x; 1.7056x over previous
//
#include <hip/hip_runtime.h>
#include <hip/hip_bf16.h>

#define N        2048
#define T_STEPS  8192
#define DIN      64
#define KW       128     // workgroups, 1 per CU
#define ROWS     16      // N / KW rows per WG
#define NTHR     256
#define SCOPE_AG __HIP_MEMORY_SCOPE_AGENT

typedef unsigned long long u64;

// ---------------------------------------------------------------------------
// Exchange protocol: ex[t&1][i] holds s_t[i] as (fp32_bits<<32)|t.
// Producers: one relaxed agent-scope 64-bit store (value+tag atom, no fence).
// Consumers: coalesced pipelined sweeps until all tags match t.
// Depth-2 flow control: every WG is both producer and consumer, so a slot
// can only advance to tag t+2 after ALL WGs consumed tag t (race-free).
// ---------------------------------------------------------------------------

__global__ void init_kernel(u64* ex0) {
    int i = threadIdx.x + blockIdx.x * blockDim.x;
    if (i < N) ex0[i] = 0ull;   // s_0 = 0.0f tagged 0; ex[1] keeps poison
                                // tags (0xAAAAAAAA matches no t in [0,8192]).
}

// ---------------------------------------------------------------------------
// persistent reservoir scan. W slice pinned in REGISTERS (4 rows x 8 float4
// = 128 VGPRs, asm-pinned so LLVM can't rematerialize the loads per step).
// Per step: coalesced spin-gather of s_t (8 x 512B wave-loads), conflict-free
// LDS stage, matvec + fused W_in·u[t] in one 64-lane butterfly, fast tanh,
// one tagged store per produced element.
// ---------------------------------------------------------------------------
extern "C" __global__ void __launch_bounds__(NTHR, 1)
reservoir_scan(const float* __restrict__ W,
               const float* __restrict__ W_in,
               const float* __restrict__ u,
               const float* __restrict__ noise,
               u64* __restrict__ ex,                 // [2][N] value+tag atoms
               __hip_bfloat16* __restrict__ states)  // [T][N]
{
    __shared__ float s_s[N];     // 8 KiB broadcast state
    __shared__ int   s_timeout;

    const int tid = threadIdx.x;
    const int wg  = blockIdx.x;
    const int wv  = tid >> 6;        // wave 0..3
    const int ln  = tid & 63;        // lane 0..63
    const int r0  = wg * ROWS;       // first global row of this WG
    const int rb  = wv * 4;          // first local row of this wave

    // --- W slice into registers: wr[r][j] = W[r0+rb+r][4*(ln+64j) .. +3] ---
    float4 wr[4][8];
    const float4* W4 = (const float4*)W;
    #pragma unroll
    for (int r = 0; r < 4; ++r)
        #pragma unroll
        for (int j = 0; j < 8; ++j)
            wr[r][j] = W4[(size_t)(r0 + rb + r) * (N / 4) + ln + 64 * j];
    // pin in VGPRs — forbid rematerialization of the loads inside the t-loop
    #pragma unroll
    for (int r = 0; r < 4; ++r)
        #pragma unroll
        for (int j = 0; j < 8; ++j)
            asm volatile("" : "+v"(wr[r][j].x), "+v"(wr[r][j].y),
                              "+v"(wr[r][j].z), "+v"(wr[r][j].w));

    // --- W_in columns: lane ln holds W_in[row][ln] (DIN == 64) ---
    float wi0 = W_in[(size_t)(r0 + rb + 0) * DIN + ln];
    float wi1 = W_in[(size_t)(r0 + rb + 1) * DIN + ln];
    float wi2 = W_in[(size_t)(r0 + rb + 2) * DIN + ln];
    float wi3 = W_in[(size_t)(r0 + rb + 3) * DIN + ln];
    if (tid == 0) s_timeout = 0;
    __syncthreads();

    const float4* s4    = (const float4*)s_s;
    const int     gbase = wv * 512 + ln;   // lane-contiguous slot base

    for (int t = 0; t < T_STEPS; ++t) {
        // independent loads issued early — overlap with the spin-gather
        float ul = u[t * DIN + ln];
        float nz = 0.0f;
        if (ln < 4) nz = noise[(size_t)t * N + r0 + rb + ln];

        // --- coalesced spin-gather: 8 x 512B wave-loads per sweep ---
        u64* exb = ex + (size_t)(t & 1) * N;
        u64 v[8];
        int guard = 0;
        for (;;) {
            #pragma unroll
            for (int i = 0; i < 8; ++i)
                v[i] = __hip_atomic_load(&exb[gbase + 64 * i],
                                         __ATOMIC_RELAXED, SCOPE_AG);
            int ok = 0;
            #pragma unroll
            for (int i = 0; i < 8; ++i)
                ok += ((unsigned)v[i] == (unsigned)t);
            if (__all(ok == 8)) break;            // wave-uniform exit
            if (++guard > (1 << 16)) { s_timeout = 1; break; }
        }
        #pragma unroll
        for (int i = 0; i < 8; ++i)               // stride-4B: conflict-free
            s_s[gbase + 64 * i] = __uint_as_float((unsigned)(v[i] >> 32));
        __syncthreads();
        if (s_timeout) return;    // uniform abort instead of an eternal hang

        // --- matvec: wave wv -> rows rb..rb+3; lane covers cols {4(ln+64j)} ---
        float a0 = wi0 * ul;      // input drive folded into the same reduction
        float a1 = wi1 * ul;
        float a2 = wi2 * ul;
        float a3 = wi3 * ul;
        #pragma unroll
        for (int j = 0; j < 8; ++j) {
            float4 sv = s4[ln + 64 * j];
            a0 += wr[0][j].x * sv.x + wr[0][j].y * sv.y + wr[0][j].z * sv.z + wr[0][j].w * sv.w;
            a1 += wr[1][j].x * sv.x + wr[1][j].y * sv.y + wr[1][j].z * sv.z + wr[1][j].w * sv.w;
            a2 += wr[2][j].x * sv.x + wr[2][j].y * sv.y + wr[2][j].z * sv.z + wr[2][j].w * sv.w;
            a3 += wr[3][j].x * sv.x + wr[3][j].y * sv.y + wr[3][j].z * sv.z + wr[3][j].w * sv.w;
        }
        #pragma unroll
        for (int off = 1; off < 64; off <<= 1) {
            a0 += __shfl_xor(a0, off, 64);
            a1 += __shfl_xor(a1, off, 64);
            a2 += __shfl_xor(a2, off, 64);
            a3 += __shfl_xor(a3, off, 64);
        }

        if (ln < 4) {
            const int gr = r0 + rb + ln;
            float acc = (ln == 0) ? a0 : (ln == 1) ? a1 : (ln == 2) ? a2 : a3;
            float pre = acc + 0.01f * nz;
            // fast tanh: sign * (1 - 2/(exp2(2*log2e*|x|)+1)) via v_exp/v_rcp
            float ax = __builtin_fabsf(pre);
            float e  = __builtin_amdgcn_exp2f(ax * 2.8853900817779268f);
            float th = 1.0f - 2.0f * __builtin_amdgcn_rcpf(e + 1.0f);
            th = __builtin_copysignf(th, pre);
            float snew = 0.7f * s_s[gr] + 0.3f * th;
            u64 pk = ((u64)__float_as_uint(snew) << 32) | (unsigned)(t + 1);
            __hip_atomic_store(&ex[(size_t)((t + 1) & 1) * N + gr], pk,
                               __ATOMIC_RELAXED, SCOPE_AG);
            states[(size_t)t * N + gr] = __float2bfloat16(snew);
        }

        __syncthreads();   // protect s_s before next step's gather overwrites
    }
}

// ---------------------------------------------------------------------------
// readout: out[t][d] = states[t] . w_out[d] + b_out[d].  One wave per t,
// lane covers cols {4c+256j}: coalesced global reads of w_out, conflict-free
// b128 LDS reads of s, full-wave butterfly per output.
// ---------------------------------------------------------------------------
__global__ void __launch_bounds__(256)
out_gemm(const __hip_bfloat16* __restrict__ states,
         const float* __restrict__ w_out,
         const float* __restrict__ b_out,
         float* __restrict__ out)
{
    __shared__ float s_lds[4][N];   // 32 KiB
    const int tid = threadIdx.x;
    const int wv  = tid >> 6, ln = tid & 63;
    const int t0  = blockIdx.x * 4;

    for (int idx = tid; idx < 4 * N; idx += 256) {
        int tt = idx >> 11, kk = idx & (N - 1);
        s_lds[tt][kk] = __bfloat162float(states[(size_t)(t0 + tt) * N + kk]);
    }
    __syncthreads();

    const int t = t0 + wv;
    const float4* s4 = (const float4*)&s_lds[wv][0];
    for (int d = 0; d < 64; ++d) {
        const float4* w4 = (const float4*)(w_out + (size_t)d * N);
        float a = 0.0f;
        #pragma unroll
        for (int j = 0; j < 8; ++j) {
            const int ci = ln + 64 * j;
            float4 wv4 = w4[ci];
            float4 sv  = s4[ci];
            a += wv4.x * sv.x + wv4.y * sv.y + wv4.z * sv.z + wv4.w * sv.w;
        }
        #pragma unroll
        for (int off = 1; off < 64; off <<= 1) a += __shfl_xor(a, off, 64);
        if (ln == 0) out[t * 64 + d] = a + b_out[d];
    }
}

// ---------------------------------------------------------------------------
extern "C" void kernel_launch(void* const* d_in, const int* in_sizes, int n_in,
                              void* d_out, int out_size, void* d_ws, size_t ws_size,
                              hipStream_t stream)
{
    const float* u     = (const float*)d_in[0];   // (T, DIN)
    const float* noise = (const float*)d_in[1];   // (T, N)
    const float* W_in  = (const float*)d_in[2];   // (N, DIN)
    const float* W     = (const float*)d_in[3];   // (N, N)
    const float* w_out = (const float*)d_in[4];   // (64, N)
    const float* b_out = (const float*)d_in[5];   // (64,)
    float* out = (float*)d_out;

    // workspace layout: [0, 32K): ex[2][N] u64 | [64K, 64K+32M): states bf16
    u64* ex                = (u64*)d_ws;
    __hip_bfloat16* states = (__hip_bfloat16*)((char*)d_ws + 65536);

    hipLaunchKernelGGL(init_kernel, dim3((N + 255) / 256), dim3(256), 0, stream,
                       ex);

    void* args[] = { (void*)&W, (void*)&W_in, (void*)&u, (void*)&noise,
                     (void*)&ex, (void*)&states };
    hipLaunchCooperativeKernel((const void*)reservoir_scan,
                               dim3(KW), dim3(NTHR), args, 0, stream);

    hipLaunchKernelGGL(out_gemm, dim3(T_STEPS / 4), dim3(256), 0, stream,
                       states, w_out, b_out, out);
}